// Round 2
// baseline (341.838 us; speedup 1.0000x reference)
//
#include <hip/hip_runtime.h>
#include <hip/hip_bf16.h>
#include <cstdint>
#include <cstddef>

typedef __hip_bfloat16 bf16;
typedef __attribute__((ext_vector_type(4))) float f32x4;
typedef __attribute__((ext_vector_type(8))) short s16x8;

// ---- async global->LDS, 16B per lane. Dest is wave-uniform base + lane*16. ----
__device__ __forceinline__ void gload_lds16(const void* g, void* l) {
    __builtin_amdgcn_global_load_lds(
        (const __attribute__((address_space(1))) unsigned int*)g,
        (__attribute__((address_space(3))) unsigned int*)l,
        16, 0, 0);
}

// =======================================================================
// f32 -> bf16 convert (grid-stride over groups of 4)
// =======================================================================
__global__ __launch_bounds__(256)
void cvt_f32_bf16(const float* __restrict__ src, bf16* __restrict__ dst, int n)
{
    int i = (blockIdx.x * 256 + threadIdx.x) * 4;
    if (i + 3 < n) {
        float4 v = *(const float4*)(src + i);
        dst[i + 0] = __float2bfloat16(v.x);
        dst[i + 1] = __float2bfloat16(v.y);
        dst[i + 2] = __float2bfloat16(v.z);
        dst[i + 3] = __float2bfloat16(v.w);
    }
}

// gather rows of AGE_inx per Endx, convert to bf16. One block per out-row.
__global__ __launch_bounds__(256)
void gather_cvt(const float* __restrict__ src, const int* __restrict__ idx,
                bf16* __restrict__ dst)
{
    int row = blockIdx.x;
    int r = idx[row];
    const float* s = src + (size_t)r * 768;
    bf16* d = dst + (size_t)row * 768;
    int c = threadIdx.x * 4;
    if (c < 768) {
        float4 v = *(const float4*)(s + c);
        d[c + 0] = __float2bfloat16(v.x);
        d[c + 1] = __float2bfloat16(v.y);
        d[c + 2] = __float2bfloat16(v.z);
        d[c + 3] = __float2bfloat16(v.w);
    }
}

// =======================================================================
// Generic GEMM:  C[m,n] = act( sum_k A[m,k]*B[n,k] + bias[n] ) * (Mul[m,n])
//   A: [M,K] bf16, B: [N,K] bf16, bias/Mul: f32.
//   Tile: BM=BN=128, BK=64. 256 threads = 4 waves, each wave 64x64 out.
//   LDS: 16B chunks; slot (row, c) holds global chunk (row, c ^ (row&7)).
// =======================================================================
template<int TANH, int MULW, int F32OUT, int NGUARD>
__global__ __launch_bounds__(256)
void gemm_bt(const bf16* __restrict__ A, const bf16* __restrict__ B,
             const float* __restrict__ bias, const float* __restrict__ Mul,
             void* __restrict__ Cout, int M, int N, int K, int ldc)
{
    __shared__ short sA[128 * 64];   // 16 KB
    __shared__ short sB[128 * 64];   // 16 KB

    const int tid  = threadIdx.x;
    const int lane = tid & 63;
    const int wave = tid >> 6;
    const int bm = blockIdx.y, bn = blockIdx.x;
    const int wr = wave >> 1, wc = wave & 1;
    const int l15 = lane & 15, quad = lane >> 4;

    f32x4 acc[4][4];
#pragma unroll
    for (int i = 0; i < 4; ++i)
#pragma unroll
        for (int j = 0; j < 4; ++j)
            acc[i][j] = (f32x4){0.f, 0.f, 0.f, 0.f};

    for (int kt = 0; kt < K; kt += 64) {
#pragma unroll
        for (int j = 0; j < 4; ++j) {
            int S   = (wave * 4 + j) * 64 + lane;      // LDS chunk slot
            int row = S >> 3;
            int cc  = (S & 7) ^ (row & 7);             // swizzled source chunk
            gload_lds16(A + (size_t)(bm * 128 + row) * K + kt + cc * 8, &sA[S * 8]);
        }
#pragma unroll
        for (int j = 0; j < 4; ++j) {
            int S   = (wave * 4 + j) * 64 + lane;
            int row = S >> 3;
            int cc  = (S & 7) ^ (row & 7);
            int ng  = bn * 128 + row;
            if (NGUARD) ng = (ng < N) ? ng : (N - 1);
            gload_lds16(B + (size_t)ng * K + kt + cc * 8, &sB[S * 8]);
        }
        asm volatile("s_waitcnt vmcnt(0)" ::: "memory");
        __syncthreads();

#pragma unroll
        for (int ks = 0; ks < 2; ++ks) {
            s16x8 afr[4], bfr[4];
#pragma unroll
            for (int i = 0; i < 4; ++i) {
                int r = wr * 64 + i * 16 + l15;
                int q = ks * 4 + quad;
                afr[i] = *(const s16x8*)&sA[(r * 8 + (q ^ (r & 7))) * 8];
            }
#pragma unroll
            for (int j = 0; j < 4; ++j) {
                int r = wc * 64 + j * 16 + l15;
                int q = ks * 4 + quad;
                bfr[j] = *(const s16x8*)&sB[(r * 8 + (q ^ (r & 7))) * 8];
            }
#pragma unroll
            for (int i = 0; i < 4; ++i)
#pragma unroll
                for (int j = 0; j < 4; ++j)
                    acc[i][j] = __builtin_amdgcn_mfma_f32_16x16x32_bf16(
                        afr[i], bfr[j], acc[i][j], 0, 0, 0);
        }
        __syncthreads();
    }

    // ---- epilogue. C/D layout: col = lane&15, row = quad*4 + reg ----
#pragma unroll
    for (int j = 0; j < 4; ++j) {
        int colg = bn * 128 + wc * 64 + j * 16 + l15;
        if (NGUARD && colg >= N) continue;
        float bv = bias[colg];
#pragma unroll
        for (int i = 0; i < 4; ++i) {
            int row0 = bm * 128 + wr * 64 + i * 16 + quad * 4;
#pragma unroll
            for (int r = 0; r < 4; ++r) {
                float v = acc[i][j][r] + bv;
                if (TANH) v = tanhf(v);
                if (MULW) v *= Mul[(size_t)(row0 + r) * N + colg];
                if (F32OUT)
                    ((float*)Cout)[(size_t)(row0 + r) * ldc + colg] = v;
                else
                    ((bf16*)Cout)[(size_t)(row0 + r) * ldc + colg] = __float2bfloat16(v);
            }
        }
    }
}

// =======================================================================
// lintrans rows: z[row,:768] (fp32) -> minmax scale -> L2 norm -> bf16
// =======================================================================
__global__ __launch_bounds__(256)
void lintrans_k(const float* __restrict__ z, bf16* __restrict__ out)
{
    __shared__ float rmin[4], rmax[4], rsum[4];
    const int row  = blockIdx.x;
    const int tid  = threadIdx.x;
    const int lane = tid & 63;
    const int wave = tid >> 6;
    const float* zr = z + (size_t)row * 768;

    float v0 = zr[tid], v1 = zr[tid + 256], v2 = zr[tid + 512];
    float mn = fminf(fminf(v0, v1), v2);
    float mx = fmaxf(fmaxf(v0, v1), v2);
#pragma unroll
    for (int o = 32; o > 0; o >>= 1) {
        mn = fminf(mn, __shfl_down(mn, o));
        mx = fmaxf(mx, __shfl_down(mx, o));
    }
    if (lane == 0) { rmin[wave] = mn; rmax[wave] = mx; }
    __syncthreads();
    float bmn = fminf(fminf(rmin[0], rmin[1]), fminf(rmin[2], rmin[3]));
    float bmx = fmaxf(fmaxf(rmax[0], rmax[1]), fmaxf(rmax[2], rmax[3]));
    float sc  = 1.f / (bmx - bmn);
    v0 = (v0 - bmn) * sc; v1 = (v1 - bmn) * sc; v2 = (v2 - bmn) * sc;
    float s = v0 * v0 + v1 * v1 + v2 * v2;
#pragma unroll
    for (int o = 32; o > 0; o >>= 1) s += __shfl_down(s, o);
    if (lane == 0) rsum[wave] = s;
    __syncthreads();
    float tot = rsum[0] + rsum[1] + rsum[2] + rsum[3];
    float inv = 1.f / fmaxf(sqrtf(tot), 1e-12f);
    out[(size_t)row * 768 + tid]       = __float2bfloat16(v0 * inv);
    out[(size_t)row * 768 + tid + 256] = __float2bfloat16(v1 * inv);
    out[(size_t)row * 768 + tid + 512] = __float2bfloat16(v2 * inv);
}

// =======================================================================
extern "C" void kernel_launch(void* const* d_in, const int* in_sizes, int n_in,
                              void* d_out, int out_size, void* d_ws, size_t ws_size,
                              hipStream_t stream)
{
    (void)in_sizes; (void)n_in; (void)out_size; (void)ws_size;

    const float* t_in   = (const float*)d_in[0];   // [8192,768]
    const float* AGEinx = (const float*)d_in[1];   // [20000,768]
    const int*   Endx   = (const int*)  d_in[2];   // [4096]
    const float* W_age  = (const float*)d_in[3];   // [768,768]
    const float* b_age  = (const float*)d_in[4];   // [768]
    const float* W_prjT = (const float*)d_in[5];   // [256,768]
    const float* b_prjT = (const float*)d_in[6];   // [256]
    const float* W_prjL = (const float*)d_in[7];   // [256,768]
    const float* b_prjL = (const float*)d_in[8];   // [256]
    const float* outW   = (const float*)d_in[9];   // [4096,256]
    const float* outb   = (const float*)d_in[10];  // [4096]
    const float* W_fc3  = (const float*)d_in[11];  // [50,256]
    const float* b_fc3  = (const float*)d_in[12];  // [50]

    char* ws = (char*)d_ws;
    size_t off = 0;
    float* z    = (float*)(ws + off);                 // 4096*768 f32 (dead after lintrans)
    bf16*  h    = (bf16*)(ws + off);                  // 8192*256 bf16 (born after z dies)
    off += (size_t)4096 * 768 * 4;                    // 12.58 MB (covers h's 4.19 MB too)
    bf16* tb    = (bf16*)(ws + off); off += (size_t)8192 * 768 * 2;
    bf16* AGEg  = (bf16*)(ws + off); off += (size_t)4096 * 768 * 2;
    bf16* Wageb = (bf16*)(ws + off); off += (size_t)768 * 768 * 2;
    bf16* WpTb  = (bf16*)(ws + off); off += (size_t)256 * 768 * 2;
    bf16* WpLb  = (bf16*)(ws + off); off += (size_t)256 * 768 * 2;
    bf16* Wfc3b = (bf16*)(ws + off); off += (size_t)50 * 256 * 2 + 64;
    bf16* AGE_E = (bf16*)(ws + off); off += (size_t)4096 * 768 * 2;
    bf16* E2    = (bf16*)(ws + off); off += (size_t)4096 * 256 * 2;

    float* o_c = (float*)d_out;                    // [8192,4096]
    float* o_f = o_c + (size_t)8192 * 4096;        // [8192,50]

    // ---- f32 -> bf16 operand conversion ----
    cvt_f32_bf16<<<6144, 256, 0, stream>>>(t_in,   tb,    8192 * 768);
    cvt_f32_bf16<<<576,  256, 0, stream>>>(W_age,  Wageb, 768 * 768);
    cvt_f32_bf16<<<192,  256, 0, stream>>>(W_prjT, WpTb,  256 * 768);
    cvt_f32_bf16<<<192,  256, 0, stream>>>(W_prjL, WpLb,  256 * 768);
    cvt_f32_bf16<<<13,   256, 0, stream>>>(W_fc3,  Wfc3b, 50 * 256);
    gather_cvt  <<<4096, 256, 0, stream>>>(AGEinx, Endx,  AGEg);

    // 1) z = AGE_inx[Endx] @ W_age^T + b_age   (fp32 out)
    gemm_bt<0,0,1,0><<<dim3(6, 32), 256, 0, stream>>>(
        AGEg, Wageb, b_age, nullptr, z, 4096, 768, 768, 768);
    // 2) AGE_E = lintrans(z)
    lintrans_k<<<4096, 256, 0, stream>>>(z, AGE_E);
    // 3) E2 = tanh(AGE_E @ W_prjL^T + b_prjL) * outW
    gemm_bt<1,1,0,0><<<dim3(2, 32), 256, 0, stream>>>(
        AGE_E, WpLb, b_prjL, outW, E2, 4096, 256, 768, 256);
    // 4) h = tanh(t @ W_prjT^T + b_prjT)
    gemm_bt<1,0,0,0><<<dim3(2, 64), 256, 0, stream>>>(
        tb, WpTb, b_prjT, nullptr, h, 8192, 256, 768, 256);
    // 5) o_c = h @ E2^T + outb  (f32 out)
    gemm_bt<0,0,1,0><<<dim3(32, 64), 256, 0, stream>>>(
        h, E2, outb, nullptr, o_c, 8192, 4096, 256, 4096);
    // 6) o_f = h @ W_fc3^T + b_fc3  (N=50, guarded, f32 out)
    gemm_bt<0,0,1,1><<<dim3(1, 64), 256, 0, stream>>>(
        h, Wfc3b, b_fc3, nullptr, o_f, 8192, 50, 256, 50);
}